// Round 10
// baseline (472.101 us; speedup 1.0000x reference)
//
#include <hip/hip_runtime.h>
#include <cstdint>

typedef unsigned short ushort_t;
typedef __bf16 bf16x8 __attribute__((ext_vector_type(8)));
typedef ushort_t u16x8 __attribute__((ext_vector_type(8)));
typedef float f32x4 __attribute__((ext_vector_type(4)));
typedef uint32_t u32x4 __attribute__((ext_vector_type(4)));

#define RMS_EPS 1.1920928955078125e-07f
// B=8 T=4096 C=256 Wh=1024 E=8 K=2 ; tokens NT=32768, pairs NP=65536

__device__ __forceinline__ ushort_t f2bf(float f) {
  uint32_t u = __builtin_bit_cast(uint32_t, f);
  u += 0x7fffu + ((u >> 16) & 1u);   // RNE
  return (ushort_t)(u >> 16);
}

__device__ __forceinline__ void g2l16(const ushort_t* g, ushort_t* l) {
  __builtin_amdgcn_global_load_lds(
      (const __attribute__((address_space(1))) uint32_t*)g,
      (__attribute__((address_space(3))) uint32_t*)l, 16, 0, 0);
}

__device__ __forceinline__ f32x4 mfma32(bf16x8 a, bf16x8 b, f32x4 c) {
  return __builtin_amdgcn_mfma_f32_16x16x32_bf16(a, b, c, 0, 0, 0);
}

// GELU via odd-poly erf approx (validated r3-r8, absmax 8.0 vs thr 41.6)
__device__ __forceinline__ float gelu1(float v) {
  float vc = fminf(fmaxf(v, -2.9f), 2.9f);   // v_med3
  float x2 = vc * vc;
  float p = fmaf(-0.000414256f, x2, 0.0107517f);
  p = fmaf(p, x2, -0.1136149f);
  p = fmaf(p, x2, 0.786301f);
  float E = vc * p;
  float t = 0.5f * v;
  return fmaf(t, E, t);
}

// LDS: pack tile (16.6KB) unioned with moe's r6-proven THREE buffers (48KB).
// r9's failure was a 2-buffer time-share needing 3 live tiles (W1 cur, W2
// cur, W1 next in flight) — GEMM1(ch+1) read W2(ch). Fixed by restoring r6.
union SmemU {
  ushort_t tile[64][130];              // pack phase (16,640 B)
  struct {
    ushort_t w1b[2][8192];             // W1 double buffer (32 KB)
    ushort_t w2b[8192];                // W2 single buffer (16 KB)
  } m;
};

// ---- ONE kernel, plain launch, manual grid barrier ----
// 512 blocks x 256 thr; launch_bounds(256,2) caps regs<=256 (r6 body ~136),
// LDS 49.2KB -> >=2 blocks/CU capacity => all 512 resident at dispatch
// (guide-sanctioned: launch_bounds + grid <= k x 256). Barrier counter in
// memset-zeroed ws (re-zeroed each graph iteration). Phase0: pack (unit=bid),
// rmsnorm (64 tok/blk), route (128 pairs/blk). Phase1: r6 moe body over
// virtual tiles v = bid, bid+512 (XCD swizzle preserved: 512%8==0).
__global__ __launch_bounds__(256, 2) void moe_all(
    const float* __restrict__ x,       // [32768][256] f32
    const float* __restrict__ rw,      // [256]
    ushort_t* __restrict__ xn,         // [32768][256] bf16 (ws)
    const float* __restrict__ W1,      // [8][256][1024]
    const float* __restrict__ W2,      // [8][1024][256]
    ushort_t* __restrict__ w1f,        // [8][32][8][2][64][8] (ws)
    ushort_t* __restrict__ w2f,        // [8][32][16][64][8]  (ws)
    const float* __restrict__ b1,      // [8][1024]
    const float* __restrict__ b2,      // [8][256]
    const int* __restrict__ eids,      // [65536]
    int* __restrict__ cnt,             // [8] (memset 0 pre-launch)
    int* __restrict__ bar,             // [1] (memset 0 pre-launch)
    int* __restrict__ lists,           // [8][65536]
    float* __restrict__ out)           // [65536][256]
{
  __shared__ __align__(16) SmemU smem;
  __shared__ int lcnt[8], lbase[8];

  int bid = blockIdx.x;
  int t = threadIdx.x;
  int lane = t & 63, l16 = lane & 15, quad = lane >> 4;
  int wave = t >> 6;

  // ================= PHASE 0a: pack W1/W2 (unit = bid, 512 units) ========
  // W1 (K=32 frags): unit = e*32768 + ch*1024 + kk*128 + nt*64 + lane;
  //   elem j = W1[e][kk*32+quad*8+j][ch*32+nt*16+l16]
  // W2 (half-interleaved, A-operand of concat-K32 GEMM2):
  //   unit U = ((e*32+ch)*16+ct)*64 + lane ;
  //   elem j   = W2[e][ch*32 +  0 + quad*4+j][ct*16+l16]
  //   elem 4+j = W2[e][ch*32 + 16 + quad*4+j][ct*16+l16]
  {
    int b = bid;
    int isW2 = b >= 256;
    const float* src; ushort_t* dst; int e, kt, wt, rs;
    if (!isW2) { e = b >> 5; kt = (b >> 3) & 3; wt = b & 7; src = W1; dst = w1f; rs = 1024; }
    else { b -= 256; e = b >> 5; kt = (b >> 1) & 15; wt = b & 1; src = W2; dst = w2f; rs = 256; }
    int k0 = kt * 64, c0 = wt * 128;
    const float* sb = src + ((size_t)e << 18) + (size_t)k0 * rs + c0;
#pragma unroll
    for (int i = 0; i < 8; ++i) {
      int f = i * 1024 + t * 4;          // [0,8192)
      int r = f >> 7, c = f & 127;
      float4 v = *reinterpret_cast<const float4*>(sb + (size_t)r * rs + c);
      ushort2 lo, hi;
      lo.x = f2bf(v.x); lo.y = f2bf(v.y); hi.x = f2bf(v.z); hi.y = f2bf(v.w);
      *reinterpret_cast<ushort2*>(&smem.tile[r][c]) = lo;
      *reinterpret_cast<ushort2*>(&smem.tile[r][c + 2]) = hi;
    }
    __syncthreads();
    if (!isW2) {
#pragma unroll
      for (int p = 0; p < 4; ++p) {
        int u = p * 256 + t;               // [0,1024)
        int kk2 = (u >> 9) & 1;
        int rr = kk2 * 32 + quad * 8;
        int nt = (u >> 6) & 1, chL = (u >> 7) & 3;
        int cc = chL * 32 + nt * 16 + l16;
        u16x8 o;
#pragma unroll
        for (int j = 0; j < 8; ++j) o[j] = smem.tile[rr + j][cc];
        size_t U = ((size_t)e * 32768) + (size_t)(wt * 4 + chL) * 1024 + (kt * 2 + kk2) * 128 + nt * 64 + lane;
        *reinterpret_cast<u16x8*>(dst + U * 8) = o;
      }
    } else {
#pragma unroll
      for (int p = 0; p < 4; ++p) {
        int u = p * 4 + wave;              // [0,16): chL(2) x ctL(8)
        int chL = u >> 3, ctL = u & 7;
        int cc = ctL * 16 + l16;
        u16x8 o;
#pragma unroll
        for (int j = 0; j < 4; ++j) o[j] = smem.tile[chL * 32 + quad * 4 + j][cc];
#pragma unroll
        for (int j = 0; j < 4; ++j) o[4 + j] = smem.tile[chL * 32 + 16 + quad * 4 + j][cc];
        size_t U = (((size_t)(e * 32 + kt * 2 + chL) * 16) + (wt * 8 + ctL)) * 64 + lane;
        *reinterpret_cast<u16x8*>(dst + U * 8) = o;
      }
    }
  }

  // ================= PHASE 0b: RMSNorm 64 tokens/block ====================
#pragma unroll 1
  for (int it = 0; it < 16; ++it) {
    int token = bid * 64 + it * 4 + wave;
    const float4* row = reinterpret_cast<const float4*>(x + (size_t)token * 256);
    float4 v = row[lane];
    float s = v.x * v.x + v.y * v.y + v.z * v.z + v.w * v.w;
#pragma unroll
    for (int off = 1; off < 64; off <<= 1) s += __shfl_xor(s, off);
    float inv = rsqrtf(s * (1.0f / 256.0f) + RMS_EPS);
    const float4* wr = reinterpret_cast<const float4*>(rw);
    float4 wv = wr[lane];
    ushort4 o;
    o.x = f2bf(v.x * inv * wv.x);
    o.y = f2bf(v.y * inv * wv.y);
    o.z = f2bf(v.z * inv * wv.z);
    o.w = f2bf(v.w * inv * wv.w);
    *reinterpret_cast<ushort4*>(xn + (size_t)token * 256 + lane * 4) = o;
  }

  // ================= PHASE 0c: route 128 pairs/block ======================
  {
    if (t < 8) lcnt[t] = 0;
    __syncthreads();
    int ee = 0, lpos = 0;
    int p = bid * 128 + t;
    if (t < 128) {
      ee = eids[p];
      lpos = atomicAdd(&lcnt[ee], 1);
    }
    __syncthreads();
    if (t < 8) lbase[t] = atomicAdd(&cnt[t], lcnt[t]);
    __syncthreads();
    if (t < 128) lists[ee * 65536 + lbase[ee] + lpos] = p;
  }

  // ================= manual grid barrier (all 512 blocks resident) ========
  __threadfence();                       // release phase-0 writes, device scope
  __syncthreads();
  if (t == 0) {
    __hip_atomic_fetch_add(bar, 1, __ATOMIC_ACQ_REL, __HIP_MEMORY_SCOPE_AGENT);
    while (__hip_atomic_load(bar, __ATOMIC_ACQUIRE, __HIP_MEMORY_SCOPE_AGENT) < (int)gridDim.x) {
      __builtin_amdgcn_s_sleep(8);
    }
  }
  __syncthreads();

  // expert counts via device-scope atomic loads (dodge stale L2)
  int cnt_l[8];
#pragma unroll
  for (int i = 0; i < 8; ++i)
    cnt_l[i] = __hip_atomic_load(&cnt[i], __ATOMIC_ACQUIRE, __HIP_MEMORY_SCOPE_AGENT);

  // ================= PHASE 1: moe (r6 body, verbatim schedule) ============
#pragma unroll 1
  for (int v = bid; v < 1032; v += 512) {
    // bijective XCD swizzle over 1032 = 8*129 (512%8==0 keeps v&7==bid&7)
    int flat = (v & 7) * 129 + (v >> 3);

    int e = -1, tile = 0, accum = 0, n_e = 0;
#pragma unroll
    for (int i = 0; i < 8; ++i) {
      int c = cnt_l[i];
      int ti = (c + 63) >> 6;
      if (e < 0 && flat < accum + ti) { e = i; tile = flat - accum; n_e = c; }
      accum += ti;
    }
    if (e < 0) continue;
    int start = tile * 64;

    const ushort_t* w1e = w1f + ((size_t)e << 18);
    const ushort_t* w2e = w2f + ((size_t)e << 18);
    const int* le = lists + e * 65536;

    // this wave's 16 token rows, register-resident
    int gi = start + wave * 16 + l16;
    int pr = le[(gi < n_e) ? gi : 0];

    // stage W1(0) into buffer 0 (latency hides under A-frag loads)
#pragma unroll
    for (int j = 0; j < 4; ++j) {
      int p = j * 4 + wave;
      g2l16(w1e + p * 512 + lane * 8, &smem.m.w1b[0][p * 512]);
    }

    // A fragments: 1 m-tile x full K=256, resident (32 VGPR)
    bf16x8 afr[8];
    {
      const u32x4* ar = reinterpret_cast<const u32x4*>(xn + (size_t)(pr >> 1) * 256);
#pragma unroll
      for (int kk = 0; kk < 8; ++kk)
        afr[kk] = __builtin_bit_cast(bf16x8, ar[kk * 4 + quad]);
    }

    f32x4 acc[16];
#pragma unroll
    for (int ct = 0; ct < 16; ++ct) acc[ct] = (f32x4){0.f, 0.f, 0.f, 0.f};

    const float* b1e = b1 + e * 1024;

#pragma unroll 1
    for (int ch = 0; ch < 32; ++ch) {
      int cur = ch & 1;
      // top: vmcnt(0)+barrier — W1(ch) staged for all; all waves off w2b
      __syncthreads();

      // stage W2(ch) -> single buffer (lands under GEMM1+GELU)
      {
        const ushort_t* n2 = w2e + ch * 8192;
#pragma unroll
        for (int j = 0; j < 4; ++j) {
          int p = j * 4 + wave;
          g2l16(n2 + p * 512 + lane * 8, &smem.m.w2b[p * 512]);
        }
      }
      // stage W1(ch+1) -> alternate buffer
      if (ch + 1 < 32) {
        const ushort_t* n1 = w1e + (ch + 1) * 8192;
#pragma unroll
        for (int j = 0; j < 4; ++j) {
          int p = j * 4 + wave;
          g2l16(n1 + p * 512 + lane * 8, &smem.m.w1b[cur ^ 1][p * 512]);
        }
      }

      // GEMM1 (swapped): hT ; 2 independent chains x 8 deep (LDS reads)
      const ushort_t* l1 = smem.m.w1b[cur];
      f32x4 ht0 = (f32x4){0.f, 0.f, 0.f, 0.f};
      f32x4 ht1 = (f32x4){0.f, 0.f, 0.f, 0.f};
#pragma unroll
      for (int kk = 0; kk < 8; ++kk) {
        bf16x8 wA = *reinterpret_cast<const bf16x8*>(l1 + ((kk * 2 + 0) * 64 + lane) * 8);
        bf16x8 wB = *reinterpret_cast<const bf16x8*>(l1 + ((kk * 2 + 1) * 64 + lane) * 8);
        ht0 = mfma32(wA, afr[kk], ht0);
        ht1 = mfma32(wB, afr[kk], ht1);
      }

      int w0 = ch * 32;
      f32x4 bia0 = *reinterpret_cast<const f32x4*>(b1e + w0 + quad * 4);
      f32x4 bia1 = *reinterpret_cast<const f32x4*>(b1e + w0 + 16 + quad * 4);

      // GELU + bf16 pack. elems 0-3 = nt0 half, 4-7 = nt1 half (r2-verified)
      u16x8 hp;
#pragma unroll
      for (int rr = 0; rr < 4; ++rr) {
        hp[rr]     = f2bf(gelu1(ht0[rr] + bia0[rr]));
        hp[4 + rr] = f2bf(gelu1(ht1[rr] + bia1[rr]));
      }
      bf16x8 hF = __builtin_bit_cast(bf16x8, hp);

      // mid: vmcnt(0)+barrier — W2(ch) staged+visible (all waves)
      __syncthreads();

      // GEMM2: yT[16 tok x 256] += W2^T . hT via K=32 MFMA (LDS reads)
#pragma unroll
      for (int ct = 0; ct < 16; ++ct) {
        bf16x8 wq = *reinterpret_cast<const bf16x8*>(smem.m.w2b + (ct * 64 + lane) * 8);
        acc[ct] = mfma32(wq, hF, acc[ct]);
      }
    }

    // epilogue: +b2, masked float4 store (4 consecutive cols per lane)
    const float* b2e = b2 + e * 256;
    if (gi < n_e) {
      float* orow = out + (size_t)pr * 256;
#pragma unroll
      for (int ct = 0; ct < 16; ++ct) {
        f32x4 bv = *reinterpret_cast<const f32x4*>(b2e + ct * 16 + quad * 4);
        f32x4 o = acc[ct] + bv;
        *reinterpret_cast<f32x4*>(orow + ct * 16 + quad * 4) = o;
      }
    }
    // no barrier needed between flats: next flat's first LDS touch is
    // W1(0)->w1b[0]; w1b[0] was last read at ch30 (pre-ch31-barrier), and
    // w2b readers are fenced by the chunk-0 top __syncthreads.
  }
}

extern "C" void kernel_launch(void* const* d_in, const int* in_sizes, int n_in,
                              void* d_out, int out_size, void* d_ws, size_t ws_size,
                              hipStream_t stream) {
  const float* x  = (const float*)d_in[0];
  const float* rw = (const float*)d_in[1];
  const float* W1 = (const float*)d_in[2];
  const float* b1 = (const float*)d_in[3];
  const float* W2 = (const float*)d_in[4];
  const float* b2 = (const float*)d_in[5];
  const int* eids = (const int*)d_in[6];
  float* out = (float*)d_out;

  char* ws = (char*)d_ws;
  ushort_t* xn  = (ushort_t*)(ws);              // 16,777,216 B
  ushort_t* w1f = (ushort_t*)(ws + 16777216);   //  4,194,304 B
  ushort_t* w2f = (ushort_t*)(ws + 20971520);   //  4,194,304 B
  int* cnt      = (int*)(ws + 25165824);        //  256 B zeroed (8 cnt + bar)
  int* bar      = (int*)(ws + 25165824 + 64);   //  barrier counter (in zeroed blk)
  int* lists    = (int*)(ws + 25166080);        //  2,097,152 B

  hipMemsetAsync(cnt, 0, 256, stream);
  moe_all<<<512, 256, 0, stream>>>(x, rw, xn, W1, W2, w1f, w2f, b1, b2,
                                   eids, cnt, bar, lists, out);
}

// Round 12
// 218.583 us; speedup vs baseline: 2.1598x; 2.1598x over previous
//
#include <hip/hip_runtime.h>
#include <cstdint>

typedef unsigned short ushort_t;
typedef __bf16 bf16x8 __attribute__((ext_vector_type(8)));
typedef ushort_t u16x8 __attribute__((ext_vector_type(8)));
typedef float f32x4 __attribute__((ext_vector_type(4)));
typedef uint32_t u32x4 __attribute__((ext_vector_type(4)));

#define RMS_EPS 1.1920928955078125e-07f
// B=8 T=4096 C=256 Wh=1024 E=8 K=2 ; tokens NT=32768, pairs NP=65536

__device__ __forceinline__ ushort_t f2bf(float f) {
  uint32_t u = __builtin_bit_cast(uint32_t, f);
  u += 0x7fffu + ((u >> 16) & 1u);   // RNE
  return (ushort_t)(u >> 16);
}

__device__ __forceinline__ void g2l16(const ushort_t* g, ushort_t* l) {
  __builtin_amdgcn_global_load_lds(
      (const __attribute__((address_space(1))) uint32_t*)g,
      (__attribute__((address_space(3))) uint32_t*)l, 16, 0, 0);
}

__device__ __forceinline__ f32x4 mfma32(bf16x8 a, bf16x8 b, f32x4 c) {
  return __builtin_amdgcn_mfma_f32_16x16x32_bf16(a, b, c, 0, 0, 0);
}

// GELU via odd-poly erf approx (validated r3-r10, absmax 8.0 vs thr 41.6)
__device__ __forceinline__ float gelu1(float v) {
  float vc = fminf(fmaxf(v, -2.9f), 2.9f);   // v_med3
  float x2 = vc * vc;
  float p = fmaf(-0.000414256f, x2, 0.0107517f);
  p = fmaf(p, x2, -0.1136149f);
  p = fmaf(p, x2, 0.786301f);
  float E = vc * p;
  float t = 0.5f * v;
  return fmaf(t, E, t);
}

// ---- fused pre-pass: rmsnorm (blocks 0..2047, 16 tokens each) |
//      pack_w (2048..2559) | route (2560..2815) ----
// rmsnorm: 4 independent token-chains per wave (4-deep load ILP).
__global__ __launch_bounds__(256) void fused_pre(
    const float* __restrict__ x, const float* __restrict__ rw,
    ushort_t* __restrict__ xn,
    const float* __restrict__ W1, const float* __restrict__ W2,
    ushort_t* __restrict__ w1f, ushort_t* __restrict__ w2f,
    const int* __restrict__ eids, int* __restrict__ cnt,
    int* __restrict__ lists) {
  __shared__ ushort_t tile[64][130];
  __shared__ int lcnt[8], lbase[8];
  int bid = blockIdx.x;
  int t = threadIdx.x;

  if (bid < 2048) {
    // ---- RMSNorm + cast to bf16: 16 tokens/block, 4 per wave ----
    int lane = t & 63;
    int wave = t >> 6;
    const float4* wr = reinterpret_cast<const float4*>(rw);
    float4 wv = wr[lane];
#pragma unroll
    for (int it = 0; it < 4; ++it) {
      int token = bid * 16 + it * 4 + wave;
      const float4* row = reinterpret_cast<const float4*>(x + (size_t)token * 256);
      float4 v = row[lane];
      float s = v.x * v.x + v.y * v.y + v.z * v.z + v.w * v.w;
#pragma unroll
      for (int off = 1; off < 64; off <<= 1) s += __shfl_xor(s, off);
      float inv = rsqrtf(s * (1.0f / 256.0f) + RMS_EPS);
      ushort4 o;
      o.x = f2bf(v.x * inv * wv.x);
      o.y = f2bf(v.y * inv * wv.y);
      o.z = f2bf(v.z * inv * wv.z);
      o.w = f2bf(v.w * inv * wv.w);
      *reinterpret_cast<ushort4*>(xn + (size_t)token * 256 + lane * 4) = o;
    }
  } else if (bid < 2560) {
    // ---- pack W1/W2 into MFMA fragment order via LDS tile ----
    // W1 (K=32 frags): unit = e*32768 + ch*1024 + kk*128 + nt*64 + lane;
    //   elem j = W1[e][kk*32+quad*8+j][ch*32+nt*16+l16]
    // W2 (half-interleaved, A-operand of concat-K32 GEMM2):
    //   unit U = ((e*32+ch)*16+ct)*64 + lane ;
    //   elem j   = W2[e][ch*32 +  0 + quad*4+j][ct*16+l16]
    //   elem 4+j = W2[e][ch*32 + 16 + quad*4+j][ct*16+l16]
    int b = bid - 2048;
    int isW2 = b >= 256;
    const float* src; ushort_t* dst; int e, kt, wt, rs;
    if (!isW2) { e = b >> 5; kt = (b >> 3) & 3; wt = b & 7; src = W1; dst = w1f; rs = 1024; }
    else { b -= 256; e = b >> 5; kt = (b >> 1) & 15; wt = b & 1; src = W2; dst = w2f; rs = 256; }
    int k0 = kt * 64, c0 = wt * 128;
    const float* sb = src + ((size_t)e << 18) + (size_t)k0 * rs + c0;
#pragma unroll
    for (int i = 0; i < 8; ++i) {
      int f = i * 1024 + t * 4;          // [0,8192)
      int r = f >> 7, c = f & 127;
      float4 v = *reinterpret_cast<const float4*>(sb + (size_t)r * rs + c);
      ushort2 lo, hi;
      lo.x = f2bf(v.x); lo.y = f2bf(v.y); hi.x = f2bf(v.z); hi.y = f2bf(v.w);
      *reinterpret_cast<ushort2*>(&tile[r][c]) = lo;
      *reinterpret_cast<ushort2*>(&tile[r][c + 2]) = hi;
    }
    __syncthreads();
    int lane = t & 63, l16 = lane & 15, quad = lane >> 4;
    int wave = t >> 6;
    if (!isW2) {
#pragma unroll
      for (int p = 0; p < 4; ++p) {
        int u = p * 256 + t;               // [0,1024)
        int kk2 = (u >> 9) & 1;
        int rr = kk2 * 32 + quad * 8;
        int nt = (u >> 6) & 1, chL = (u >> 7) & 3;
        int cc = chL * 32 + nt * 16 + l16;
        u16x8 o;
#pragma unroll
        for (int j = 0; j < 8; ++j) o[j] = tile[rr + j][cc];
        size_t U = ((size_t)e * 32768) + (size_t)(wt * 4 + chL) * 1024 + (kt * 2 + kk2) * 128 + nt * 64 + lane;
        *reinterpret_cast<u16x8*>(dst + U * 8) = o;
      }
    } else {
#pragma unroll
      for (int p = 0; p < 4; ++p) {
        int u = p * 4 + wave;              // [0,16): chL(2) x ctL(8)
        int chL = u >> 3, ctL = u & 7;
        int cc = ctL * 16 + l16;
        u16x8 o;
#pragma unroll
        for (int j = 0; j < 4; ++j) o[j] = tile[chL * 32 + quad * 4 + j][cc];
#pragma unroll
        for (int j = 0; j < 4; ++j) o[4 + j] = tile[chL * 32 + 16 + quad * 4 + j][cc];
        size_t U = (((size_t)(e * 32 + kt * 2 + chL) * 16) + (wt * 8 + ctL)) * 64 + lane;
        *reinterpret_cast<u16x8*>(dst + U * 8) = o;
      }
    }
  } else {
    // ---- route (t,k) pairs into per-expert lists ----
    if (t < 8) lcnt[t] = 0;
    __syncthreads();
    int p = (bid - 2560) * 256 + t;
    int e = eids[p];
    int lpos = atomicAdd(&lcnt[e], 1);
    __syncthreads();
    if (t < 8) lbase[t] = atomicAdd(&cnt[t], lcnt[t]);
    __syncthreads();
    lists[e * 65536 + lbase[e] + lpos] = p;
  }
}

// ---- fused expert MLP: BYTE-IDENTICAL to round 6's 121.0us kernel ----
// 64 pairs/block, 4 waves x 16 rows. Counted-vmcnt pipeline (T4), setprio
// (T5), XCD swizzle. This is the measured session optimum; all structural
// deviations (mt=2, global-W2, fusion) regressed 50-250%.
__global__ __launch_bounds__(256, 3) void moe_mlp(
    const ushort_t* __restrict__ xn,   // [32768][256] bf16
    const ushort_t* __restrict__ w1f,  // [8][32][8][2][64][8]
    const ushort_t* __restrict__ w2f,  // [8][32][16][64][8]
    const float* __restrict__ b1,      // [8][1024]
    const float* __restrict__ b2,      // [8][256]
    const int* __restrict__ cnt,       // [8]
    const int* __restrict__ lists,     // [8][65536]
    float* __restrict__ out)           // [65536][256]
{
  __shared__ __align__(16) ushort_t w1b[2][8192];   // 2 x 16KB
  __shared__ __align__(16) ushort_t w2b[8192];      // 1 x 16KB

  // bijective XCD swizzle; gridDim.x = 1032 = 8*129 exactly
  int cpx = gridDim.x >> 3;
  int flat = (blockIdx.x & 7) * cpx + (blockIdx.x >> 3);

  int e = -1, tile = 0, accum = 0, n_e = 0;
#pragma unroll
  for (int i = 0; i < 8; ++i) {
    int c = cnt[i];
    int ti = (c + 63) >> 6;
    if (e < 0 && flat < accum + ti) { e = i; tile = flat - accum; n_e = c; }
    accum += ti;
  }
  if (e < 0) return;
  int start = tile * 64;

  int tid = threadIdx.x;
  int wave = tid >> 6, lane = tid & 63, l16 = lane & 15, quad = lane >> 4;

  const ushort_t* w1e = w1f + ((size_t)e << 18);
  const ushort_t* w2e = w2f + ((size_t)e << 18);
  const int* le = lists + e * 65536;

  // this wave's 16 token rows, register-resident
  int gi = start + wave * 16 + l16;
  int pr = le[(gi < n_e) ? gi : 0];

  // stage W1(0) into buffer 0 (16 x 1KB units across 4 waves)
#pragma unroll
  for (int j = 0; j < 4; ++j) {
    int p = j * 4 + wave;
    g2l16(w1e + p * 512 + lane * 8, &w1b[0][p * 512]);
  }

  // A fragments: 1 m-tile x full K=256, resident (32 VGPR)
  bf16x8 afr[8];
  {
    const u32x4* ar = reinterpret_cast<const u32x4*>(xn + (size_t)(pr >> 1) * 256);
#pragma unroll
    for (int kk = 0; kk < 8; ++kk)
      afr[kk] = __builtin_bit_cast(bf16x8, ar[kk * 4 + quad]);
  }

  f32x4 acc[16];
#pragma unroll
  for (int ct = 0; ct < 16; ++ct) acc[ct] = (f32x4){0.f, 0.f, 0.f, 0.f};

  const float* b1e = b1 + e * 1024;

  for (int ch = 0; ch < 32; ++ch) {
    int cur = ch & 1;
    // ---- top barrier: W1(ch) landed (own vmcnt), all waves off w2b ----
    asm volatile("s_waitcnt vmcnt(0)" ::: "memory");
    __builtin_amdgcn_s_barrier();
    __builtin_amdgcn_sched_barrier(0);

    // biases FIRST in vmem issue order (so mid vmcnt(4) retires them)
    int w0 = ch * 32;
    f32x4 bia0 = *reinterpret_cast<const f32x4*>(b1e + w0 + quad * 4);
    f32x4 bia1 = *reinterpret_cast<const f32x4*>(b1e + w0 + 16 + quad * 4);
    __builtin_amdgcn_sched_barrier(0);

    // stage W2(ch) -> single buffer   [vmem ops 3..6 this chunk]
    {
      const ushort_t* n2 = w2e + ch * 8192;
#pragma unroll
      for (int j = 0; j < 4; ++j) {
        int p = j * 4 + wave;
        g2l16(n2 + p * 512 + lane * 8, &w2b[p * 512]);
      }
    }
    __builtin_amdgcn_sched_barrier(0);
    // stage W1(ch+1) -> alternate buffer   [vmem ops 7..10; stay in flight
    // across the mid barrier]
    if (ch + 1 < 32) {
      const ushort_t* n1 = w1e + (ch + 1) * 8192;
#pragma unroll
      for (int j = 0; j < 4; ++j) {
        int p = j * 4 + wave;
        g2l16(n1 + p * 512 + lane * 8, &w1b[cur ^ 1][p * 512]);
      }
    }
    __builtin_amdgcn_sched_barrier(0);

    // GEMM1 (swapped): hT ; 2 independent chains x 8 deep
    const ushort_t* l1 = w1b[cur];
    f32x4 ht0 = (f32x4){0.f, 0.f, 0.f, 0.f};
    f32x4 ht1 = (f32x4){0.f, 0.f, 0.f, 0.f};
    __builtin_amdgcn_s_setprio(1);
#pragma unroll
    for (int kk = 0; kk < 8; ++kk) {
      bf16x8 wA = *reinterpret_cast<const bf16x8*>(l1 + ((kk * 2 + 0) * 64 + lane) * 8);
      bf16x8 wB = *reinterpret_cast<const bf16x8*>(l1 + ((kk * 2 + 1) * 64 + lane) * 8);
      ht0 = mfma32(wA, afr[kk], ht0);
      ht1 = mfma32(wB, afr[kk], ht1);
    }
    __builtin_amdgcn_s_setprio(0);

    // GELU + bf16 pack in registers. elems 0-3 = nt0 half, 4-7 = nt1 half
    // — matches W2 frag interleave (r2-verified).
    u16x8 hp;
#pragma unroll
    for (int rr = 0; rr < 4; ++rr) {
      hp[rr]     = f2bf(gelu1(ht0[rr] + bia0[rr]));
      hp[4 + rr] = f2bf(gelu1(ht1[rr] + bia1[rr]));
    }
    bf16x8 hF = __builtin_bit_cast(bf16x8, hp);

    // ---- mid barrier: W2(ch) retired (FIFO: bias2,W2x4 are the oldest 6);
    // W1(ch+1)'s 4 loads remain outstanding across the barrier ----
    if (ch < 31) {
      asm volatile("s_waitcnt vmcnt(4)" ::: "memory");
    } else {
      asm volatile("s_waitcnt vmcnt(0)" ::: "memory");
    }
    __builtin_amdgcn_s_barrier();
    __builtin_amdgcn_sched_barrier(0);

    // GEMM2: yT[16 tok x 256] += W2^T . hT via K=32 MFMA; 16 indep accs
    __builtin_amdgcn_s_setprio(1);
#pragma unroll
    for (int ct = 0; ct < 16; ++ct) {
      bf16x8 wq = *reinterpret_cast<const bf16x8*>(w2b + (ct * 64 + lane) * 8);
      acc[ct] = mfma32(wq, hF, acc[ct]);
    }
    __builtin_amdgcn_s_setprio(0);
  }

  // epilogue: +b2, masked float4 store (4 consecutive cols per lane)
  const float* b2e = b2 + e * 256;
  if (gi < n_e) {
    float* orow = out + (size_t)pr * 256;
#pragma unroll
    for (int ct = 0; ct < 16; ++ct) {
      f32x4 bv = *reinterpret_cast<const f32x4*>(b2e + ct * 16 + quad * 4);
      f32x4 o = acc[ct] + bv;
      *reinterpret_cast<f32x4*>(orow + ct * 16 + quad * 4) = o;
    }
  }
}

extern "C" void kernel_launch(void* const* d_in, const int* in_sizes, int n_in,
                              void* d_out, int out_size, void* d_ws, size_t ws_size,
                              hipStream_t stream) {
  const float* x  = (const float*)d_in[0];
  const float* rw = (const float*)d_in[1];
  const float* W1 = (const float*)d_in[2];
  const float* b1 = (const float*)d_in[3];
  const float* W2 = (const float*)d_in[4];
  const float* b2 = (const float*)d_in[5];
  const int* eids = (const int*)d_in[6];
  float* out = (float*)d_out;

  char* ws = (char*)d_ws;
  ushort_t* xn  = (ushort_t*)(ws);              // 16,777,216 B
  ushort_t* w1f = (ushort_t*)(ws + 16777216);   //  4,194,304 B
  ushort_t* w2f = (ushort_t*)(ws + 20971520);   //  4,194,304 B
  int* cnt      = (int*)(ws + 25165824);        //  256 B (8 used)
  int* lists    = (int*)(ws + 25166080);        //  2,097,152 B

  hipMemsetAsync(cnt, 0, 8 * sizeof(int), stream);
  // one fused pre-pass dispatch: rmsnorm (2048) + pack_w (512) + route (256)
  fused_pre<<<2816, 256, 0, stream>>>(x, rw, xn, W1, W2, w1f, w2f, eids, cnt, lists);
  // max tiles = sum_e ceil(c_e/64) <= 65536/64 + 8 = 1032 (= 8*129)
  moe_mlp<<<1032, 256, 0, stream>>>(xn, w1f, w2f, b1, b2, cnt, lists, out);
}